// Round 1
// baseline (208.310 us; speedup 1.0000x reference)
//
#include <hip/hip_runtime.h>

#define Bn 8
#define Tn 1024
#define Fn 128
#define Hn 64
#define NC 32
#define CSZ 32

constexpr float EPS = 1e-5f;

__device__ __forceinline__ void fma4(float4& a, float s, const float4& w) {
    a.x = fmaf(s, w.x, a.x); a.y = fmaf(s, w.y, a.y);
    a.z = fmaf(s, w.z, a.z); a.w = fmaf(s, w.w, a.w);
}
__device__ __forceinline__ float4 f4zero() { return make_float4(0.f, 0.f, 0.f, 0.f); }

// ---------------- K1a: LayerNorm. one wave per token ----------------
__global__ __launch_bounds__(256) void k_ln(const float* __restrict__ x,
                                            const float* __restrict__ gamma,
                                            const float* __restrict__ beta,
                                            float* __restrict__ xn) {
    const int w = threadIdx.x >> 6, lane = threadIdx.x & 63;
    const int tok = blockIdx.x * 4 + w;
    const float2 xv = *(const float2*)(x + tok * Fn + lane * 2);
    float s  = xv.x + xv.y;
    float ss = xv.x * xv.x + xv.y * xv.y;
#pragma unroll
    for (int m = 1; m < 64; m <<= 1) { s += __shfl_xor(s, m); ss += __shfl_xor(ss, m); }
    const float mu  = s * (1.0f / Fn);
    const float var = ss * (1.0f / Fn) - mu * mu;
    const float rs  = rsqrtf(var + EPS);
    const float2 g  = *(const float2*)(gamma + lane * 2);
    const float2 bt = *(const float2*)(beta + lane * 2);
    float2 o;
    o.x = (xv.x - mu) * rs * g.x + bt.x;
    o.y = (xv.y - mu) * rs * g.y + bt.y;
    *(float2*)(xn + tok * Fn + lane * 2) = o;
}

// ---------------- K1b: projections GEMM [8192x128]@[128x256] ----------------
// block: 32 tokens x 256 outputs (K|Q|V|Ws concat). thread: 8 tok x 4 out.
__global__ __launch_bounds__(256) void k_proj(const float* __restrict__ xn,
                                              const float* __restrict__ Wk,
                                              const float* __restrict__ Wq,
                                              const float* __restrict__ Wv,
                                              const float* __restrict__ Wsp,
                                              const float* __restrict__ bs,
                                              float* __restrict__ Kb, float* __restrict__ Qb,
                                              float* __restrict__ Vb, float* __restrict__ Rb) {
    __shared__ float LW[32 * 260];  // [k in chunk][out 0..255], pad 260 (16B-aligned rows)
    __shared__ float LX[32 * 36];   // [k in chunk][token 0..31], pad 36
    const int tid  = threadIdx.x;
    const int tok0 = blockIdx.x * 32;
    const int tg   = tid >> 6;   // token group (8 tokens)
    const int cg   = tid & 63;   // output quad index

    const int   ms   = tid >> 6;
    const float* WmS = (ms == 0) ? Wk : (ms == 1) ? Wq : (ms == 2) ? Wv : Wsp;
    const float* wrow = WmS + (tid & 63) * Fn;

    float4 acc[8];
#pragma unroll
    for (int i = 0; i < 8; i++) acc[i] = f4zero();

    for (int kc0 = 0; kc0 < Fn; kc0 += 32) {
        // stage weights (transposed): LW[k][o=tid]
#pragma unroll
        for (int r = 0; r < 8; r++) {
            const float4 wv = *(const float4*)(wrow + kc0 + r * 4);
            LW[(r * 4 + 0) * 260 + tid] = wv.x;
            LW[(r * 4 + 1) * 260 + tid] = wv.y;
            LW[(r * 4 + 2) * 260 + tid] = wv.z;
            LW[(r * 4 + 3) * 260 + tid] = wv.w;
        }
        // stage xn (transposed): LX[k][tok]
        {
            const int tt = tid >> 3, kk = (tid & 7) * 4;
            const float4 xv = *(const float4*)(xn + (tok0 + tt) * Fn + kc0 + kk);
            LX[(kk + 0) * 36 + tt] = xv.x;
            LX[(kk + 1) * 36 + tt] = xv.y;
            LX[(kk + 2) * 36 + tt] = xv.z;
            LX[(kk + 3) * 36 + tt] = xv.w;
        }
        __syncthreads();
#pragma unroll 8
        for (int kc = 0; kc < 32; kc++) {
            const float4 w4 = *(const float4*)&LW[kc * 260 + cg * 4];
            const float4 xa = *(const float4*)&LX[kc * 36 + tg * 8];
            const float4 xb = *(const float4*)&LX[kc * 36 + tg * 8 + 4];
            fma4(acc[0], xa.x, w4); fma4(acc[1], xa.y, w4);
            fma4(acc[2], xa.z, w4); fma4(acc[3], xa.w, w4);
            fma4(acc[4], xb.x, w4); fma4(acc[5], xb.y, w4);
            fma4(acc[6], xb.z, w4); fma4(acc[7], xb.w, w4);
        }
        __syncthreads();
    }
    const int m  = cg >> 4;
    const int h0 = (cg & 15) * 4;
    float* outp = (m == 0) ? Kb : (m == 1) ? Qb : (m == 2) ? Vb : Rb;
    if (m < 2) {  // relu for K, Q
#pragma unroll
        for (int i = 0; i < 8; i++) {
            acc[i].x = fmaxf(acc[i].x, 0.f); acc[i].y = fmaxf(acc[i].y, 0.f);
            acc[i].z = fmaxf(acc[i].z, 0.f); acc[i].w = fmaxf(acc[i].w, 0.f);
        }
    } else if (m == 3) {  // shortcut projection gets +bs here
        const float4 bv = *(const float4*)(bs + h0);
#pragma unroll
        for (int i = 0; i < 8; i++) {
            acc[i].x += bv.x; acc[i].y += bv.y; acc[i].z += bv.z; acc[i].w += bv.w;
        }
    }
#pragma unroll
    for (int ti = 0; ti < 8; ti++)
        *(float4*)(outp + (tok0 + tg * 8 + ti) * Hn + h0) = acc[ti];
}

// ---------------- K1c: sum-normalize K and Q. one wave per (token, which) ----------------
__global__ __launch_bounds__(256) void k_sumnorm(float* __restrict__ Kb, float* __restrict__ Qb) {
    const int w = threadIdx.x >> 6, lane = threadIdx.x & 63;
    const int tok = blockIdx.x * 2 + (w & 1);
    float* buf = (w >> 1) ? Qb : Kb;
    const float v = buf[tok * Hn + lane];
    float s = v;
#pragma unroll
    for (int m = 1; m < 64; m <<= 1) s += __shfl_xor(s, m);
    buf[tok * Hn + lane] = v / (EPS + s);
}

// ---------------- K2: per-chunk kv outer-product sums ----------------
__global__ __launch_bounds__(256) void k_csum(const float* __restrict__ Kb,
                                              const float* __restrict__ Vb,
                                              float* __restrict__ csum) {
    __shared__ float Kc[CSZ * Hn];
    __shared__ float Vc[CSZ * Hn];
    const int tid = threadIdx.x;
    const int b = blockIdx.x >> 5, c = blockIdx.x & 31;
    const int t0 = c * CSZ;
    const float4* Kg = (const float4*)(Kb + (b * Tn + t0) * Hn);
    const float4* Vg = (const float4*)(Vb + (b * Tn + t0) * Hn);
#pragma unroll
    for (int r = 0; r < 2; r++) {
        ((float4*)Kc)[tid + 256 * r] = Kg[tid + 256 * r];
        ((float4*)Vc)[tid + 256 * r] = Vg[tid + 256 * r];
    }
    __syncthreads();
    float4 acc[4];
#pragma unroll
    for (int s = 0; s < 4; s++) acc[s] = f4zero();
    const int jq = tid & 15, rr = tid >> 4;
    for (int t = 0; t < CSZ; t++) {
        const float4 kv = ((const float4*)Kc)[t * 16 + jq];
#pragma unroll
        for (int s = 0; s < 4; s++) {
            const float v = Vc[t * Hn + s * 16 + rr];
            fma4(acc[s], v, kv);
        }
    }
    float4* out = (float4*)(csum + (size_t)(b * NC + c) * Hn * Hn);
#pragma unroll
    for (int s = 0; s < 4; s++) out[s * 256 + tid] = acc[s];
}

// ---------------- K3: exclusive scan over chunks, parallel over state elements ----------------
__global__ __launch_bounds__(256) void k_scan(const float* __restrict__ state,
                                              const float* __restrict__ csum,
                                              float* __restrict__ cstart) {
    const int b = blockIdx.x >> 4, et = blockIdx.x & 15;
    const int e = et * 256 + threadIdx.x;
    float v[NC];
#pragma unroll
    for (int c = 0; c < NC; c++) v[c] = csum[(size_t)(b * NC + c) * 4096 + e];
    float acc = state[b * 4096 + e];
#pragma unroll
    for (int c = 0; c < NC; c++) {
        cstart[(size_t)(b * NC + c) * 4096 + e] = acc;
        acc += v[c];
    }
}

// ---------------- K4: main — replay chunk, stream S, compute y ----------------
__global__ __launch_bounds__(256) void k_main(const float* __restrict__ Kb,
                                              const float* __restrict__ Qb,
                                              const float* __restrict__ Vb,
                                              const float* __restrict__ cstart,
                                              float* __restrict__ yraw,
                                              float* __restrict__ outS) {
    __shared__ float Kc[CSZ * Hn];
    __shared__ float Qc[CSZ * Hn];
    __shared__ float Vc[CSZ * Hn];
    const int tid = threadIdx.x;
    const int b = blockIdx.x >> 5, c = blockIdx.x & 31;
    const int t0 = c * CSZ;
    const float4* Kg = (const float4*)(Kb + (b * Tn + t0) * Hn);
    const float4* Qg = (const float4*)(Qb + (b * Tn + t0) * Hn);
    const float4* Vg = (const float4*)(Vb + (b * Tn + t0) * Hn);
#pragma unroll
    for (int r = 0; r < 2; r++) {
        ((float4*)Kc)[tid + 256 * r] = Kg[tid + 256 * r];
        ((float4*)Qc)[tid + 256 * r] = Qg[tid + 256 * r];
        ((float4*)Vc)[tid + 256 * r] = Vg[tid + 256 * r];
    }
    float4 S4[4];
    const float4* cs = (const float4*)(cstart + (size_t)(b * NC + c) * 4096);
#pragma unroll
    for (int s = 0; s < 4; s++) S4[s] = cs[s * 256 + tid];
    __syncthreads();
    const int jq = tid & 15, rr = tid >> 4;
    float* yBase = yraw + (b * Tn + t0) * Hn;
    float4* SBase = (float4*)outS + (size_t)(b * Tn + t0) * 1024;  // 1024 float4 per t
    for (int t = 0; t < CSZ; t++) {
        const float4 kv = ((const float4*)Kc)[t * 16 + jq];
        const float4 qv = ((const float4*)Qc)[t * 16 + jq];
        float yp[4];
#pragma unroll
        for (int s = 0; s < 4; s++) {
            const float v = Vc[t * Hn + s * 16 + rr];
            fma4(S4[s], v, kv);
            yp[s] = S4[s].x * qv.x + S4[s].y * qv.y + S4[s].z * qv.z + S4[s].w * qv.w;
        }
        float4* So = SBase + t * 1024;
#pragma unroll
        for (int s = 0; s < 4; s++) So[s * 256 + tid] = S4[s];  // block-coalesced 4KiB stores
#pragma unroll
        for (int s = 0; s < 4; s++) {
            yp[s] += __shfl_xor(yp[s], 1);
            yp[s] += __shfl_xor(yp[s], 2);
            yp[s] += __shfl_xor(yp[s], 4);
            yp[s] += __shfl_xor(yp[s], 8);
        }
        if (jq == 0) {
#pragma unroll
            for (int s = 0; s < 4; s++) yBase[t * Hn + s * 16 + rr] = yp[s];
        }
    }
}

// ---------------- K5: FFN (2x 64x64 + relu) + residual ----------------
// block: 32 tokens. thread: 2 tok x 4 h.
__global__ __launch_bounds__(256) void k_ffn(const float* __restrict__ yraw,
                                             const float* __restrict__ W1,
                                             const float* __restrict__ b1,
                                             const float* __restrict__ W2,
                                             const float* __restrict__ b2,
                                             const float* __restrict__ Rb,
                                             float* __restrict__ outY) {
    __shared__ float WT[2][64 * 68];  // [k][h]
    __shared__ float Yt[64 * 36];     // [k][tok]
    __shared__ float Y2[64 * 36];
    __shared__ float Lb[2][64];
    const int tid = threadIdx.x;
    const int tok0 = blockIdx.x * 32;
    for (int mat = 0; mat < 2; mat++) {
        const float4* Wg = (const float4*)(mat ? W2 : W1);
#pragma unroll
        for (int r = 0; r < 4; r++) {
            const int f4i = tid + 256 * r;   // 0..1023
            const float4 wv = Wg[f4i];
            const int h = f4i >> 4;          // flat/64
            const int k = (f4i & 15) * 4;
            WT[mat][(k + 0) * 68 + h] = wv.x;
            WT[mat][(k + 1) * 68 + h] = wv.y;
            WT[mat][(k + 2) * 68 + h] = wv.z;
            WT[mat][(k + 3) * 68 + h] = wv.w;
        }
    }
    if (tid < 64) Lb[0][tid] = b1[tid];
    else if (tid < 128) Lb[1][tid - 64] = b2[tid - 64];
    {
        const float4* Yg = (const float4*)(yraw + tok0 * Hn);
#pragma unroll
        for (int r = 0; r < 2; r++) {
            const int f4i = tid + 256 * r;   // 0..511
            const float4 yv = Yg[f4i];
            const int tok = f4i >> 4;
            const int k = (f4i & 15) * 4;
            Yt[(k + 0) * 36 + tok] = yv.x;
            Yt[(k + 1) * 36 + tok] = yv.y;
            Yt[(k + 2) * 36 + tok] = yv.z;
            Yt[(k + 3) * 36 + tok] = yv.w;
        }
    }
    __syncthreads();
    const int tg = tid >> 4, cg = tid & 15;  // tokens tg*2,tg*2+1; outputs cg*4..+3
    float4 a0 = f4zero(), a1 = f4zero();
#pragma unroll 16
    for (int k = 0; k < 64; k++) {
        const float2 y2 = *(const float2*)&Yt[k * 36 + tg * 2];
        const float4 w4 = *(const float4*)&WT[0][k * 68 + cg * 4];
        fma4(a0, y2.x, w4); fma4(a1, y2.y, w4);
    }
    {
        const float4 bv = *(const float4*)&Lb[0][cg * 4];
        a0.x = fmaxf(a0.x + bv.x, 0.f); a0.y = fmaxf(a0.y + bv.y, 0.f);
        a0.z = fmaxf(a0.z + bv.z, 0.f); a0.w = fmaxf(a0.w + bv.w, 0.f);
        a1.x = fmaxf(a1.x + bv.x, 0.f); a1.y = fmaxf(a1.y + bv.y, 0.f);
        a1.z = fmaxf(a1.z + bv.z, 0.f); a1.w = fmaxf(a1.w + bv.w, 0.f);
    }
    Y2[(cg * 4 + 0) * 36 + tg * 2] = a0.x;
    Y2[(cg * 4 + 1) * 36 + tg * 2] = a0.y;
    Y2[(cg * 4 + 2) * 36 + tg * 2] = a0.z;
    Y2[(cg * 4 + 3) * 36 + tg * 2] = a0.w;
    Y2[(cg * 4 + 0) * 36 + tg * 2 + 1] = a1.x;
    Y2[(cg * 4 + 1) * 36 + tg * 2 + 1] = a1.y;
    Y2[(cg * 4 + 2) * 36 + tg * 2 + 1] = a1.z;
    Y2[(cg * 4 + 3) * 36 + tg * 2 + 1] = a1.w;
    __syncthreads();
    float4 c0 = f4zero(), c1 = f4zero();
#pragma unroll 16
    for (int k = 0; k < 64; k++) {
        const float2 y2 = *(const float2*)&Y2[k * 36 + tg * 2];
        const float4 w4 = *(const float4*)&WT[1][k * 68 + cg * 4];
        fma4(c0, y2.x, w4); fma4(c1, y2.y, w4);
    }
    const int tokA = tok0 + tg * 2, tokB = tokA + 1;
    const float4 bv = *(const float4*)&Lb[1][cg * 4];
    const float4 r0 = *(const float4*)(Rb + tokA * Hn + cg * 4);
    const float4 r1 = *(const float4*)(Rb + tokB * Hn + cg * 4);
    float4 o0, o1;
    o0.x = fmaxf(c0.x + bv.x, 0.f) + r0.x; o0.y = fmaxf(c0.y + bv.y, 0.f) + r0.y;
    o0.z = fmaxf(c0.z + bv.z, 0.f) + r0.z; o0.w = fmaxf(c0.w + bv.w, 0.f) + r0.w;
    o1.x = fmaxf(c1.x + bv.x, 0.f) + r1.x; o1.y = fmaxf(c1.y + bv.y, 0.f) + r1.y;
    o1.z = fmaxf(c1.z + bv.z, 0.f) + r1.z; o1.w = fmaxf(c1.w + bv.w, 0.f) + r1.w;
    *(float4*)(outY + tokA * Hn + cg * 4) = o0;
    *(float4*)(outY + tokB * Hn + cg * 4) = o1;
}

extern "C" void kernel_launch(void* const* d_in, const int* in_sizes, int n_in,
                              void* d_out, int out_size, void* d_ws, size_t ws_size,
                              hipStream_t stream) {
    const float* x     = (const float*)d_in[0];
    const float* state = (const float*)d_in[1];
    const float* Wk    = (const float*)d_in[2];
    const float* Wq    = (const float*)d_in[3];
    const float* Wv    = (const float*)d_in[4];
    const float* gamma = (const float*)d_in[5];
    const float* beta  = (const float*)d_in[6];
    const float* W1    = (const float*)d_in[7];
    const float* b1    = (const float*)d_in[8];
    const float* W2    = (const float*)d_in[9];
    const float* b2    = (const float*)d_in[10];
    const float* Wsp   = (const float*)d_in[11];
    const float* bs    = (const float*)d_in[12];

    float* ws     = (float*)d_ws;
    float* Kb     = ws;                 // 524288
    float* Qb     = ws + 524288;        // 524288
    float* Vb     = ws + 1048576;       // 524288
    float* Rb     = ws + 1572864;       // 524288
    float* yraw   = ws + 2097152;       // 524288
    float* csum   = ws + 2621440;       // 1048576
    float* cstart = ws + 3670016;       // 1048576
    float* xn     = ws + 4718592;       // 1048576  (total 23.1 MB)

    float* outY = (float*)d_out;
    float* outS = outY + (size_t)Bn * Tn * Hn;  // y first, then S

    k_ln<<<2048, 256, 0, stream>>>(x, gamma, beta, xn);
    k_proj<<<256, 256, 0, stream>>>(xn, Wk, Wq, Wv, Wsp, bs, Kb, Qb, Vb, Rb);
    k_sumnorm<<<4096, 256, 0, stream>>>(Kb, Qb);
    k_csum<<<256, 256, 0, stream>>>(Kb, Vb, csum);
    k_scan<<<128, 256, 0, stream>>>(state, csum, cstart);
    k_main<<<256, 256, 0, stream>>>(Kb, Qb, Vb, cstart, yraw, outS);
    k_ffn<<<256, 256, 0, stream>>>(yraw, W1, b1, W2, b2, Rb, outY);
}

// Round 3
// 194.426 us; speedup vs baseline: 1.0714x; 1.0714x over previous
//
#include <hip/hip_runtime.h>

#define Bn 8
#define Tn 1024
#define Fn 128
#define Hn 64
#define NC 64      // chunks per batch (16 tokens each)
#define CSZ 16     // tokens per chunk in k3

constexpr float EPS = 1e-5f;

__device__ __forceinline__ void fma4(float4& a, float s, const float4& w) {
    a.x = fmaf(s, w.x, a.x); a.y = fmaf(s, w.y, a.y);
    a.z = fmaf(s, w.z, a.z); a.w = fmaf(s, w.w, a.w);
}
__device__ __forceinline__ float4 f4zero() { return make_float4(0.f, 0.f, 0.f, 0.f); }

// ---------------- K1: LN + projections + relu + sumnorm + chunk kv-sums ----------------
// block: 32 tokens. GEMM [32x128]@[128x256] (K|Q|V|Ws). Then per-chunk kv outer sums.
__global__ __launch_bounds__(256) void k1_proj(
    const float* __restrict__ x, const float* __restrict__ gamma, const float* __restrict__ beta,
    const float* __restrict__ Wk, const float* __restrict__ Wq, const float* __restrict__ Wv,
    const float* __restrict__ Wsp, const float* __restrict__ bs,
    float* __restrict__ Kb, float* __restrict__ Qb, float* __restrict__ Vb, float* __restrict__ Rb,
    float* __restrict__ csum) {
    __shared__ float LW[32 * 260];   // [k in chunk][out 0..255]
    __shared__ float LX[32 * 36];    // [k in chunk][token 0..31]
    __shared__ float Kc[32 * Hn];    // normalized K for the block's 32 tokens
    __shared__ float Vc[32 * Hn];    // V
    const int tid  = threadIdx.x;
    const int tok0 = blockIdx.x * 32;
    const int tg   = tid >> 6;   // token group of 8 (also the wave index)
    const int cg   = tid & 63;   // output quad index (o = cg*4..cg*4+3)

    const float* WmS  = (tg == 0) ? Wk : (tg == 1) ? Wq : (tg == 2) ? Wv : Wsp;
    const float* wrow = WmS + (tid & 63) * Fn;

    // --- LayerNorm: thread owns token tt, features {c*32 + kk .. +3} for c=0..3 ---
    const int tt = tid >> 3, kk = (tid & 7) * 4;
    float4 xreg[4];
    float s = 0.f, ss = 0.f;
#pragma unroll
    for (int c = 0; c < 4; c++) {
        xreg[c] = *(const float4*)(x + (tok0 + tt) * Fn + c * 32 + kk);
        s  += xreg[c].x + xreg[c].y + xreg[c].z + xreg[c].w;
        ss += xreg[c].x * xreg[c].x + xreg[c].y * xreg[c].y
            + xreg[c].z * xreg[c].z + xreg[c].w * xreg[c].w;
    }
#pragma unroll
    for (int m = 1; m < 8; m <<= 1) { s += __shfl_xor(s, m); ss += __shfl_xor(ss, m); }
    const float mu = s * (1.f / Fn);
    const float rs = rsqrtf(ss * (1.f / Fn) - mu * mu + EPS);

    float4 acc[8];
#pragma unroll
    for (int i = 0; i < 8; i++) acc[i] = f4zero();

    for (int c = 0; c < 4; c++) {
        const int kc0 = c * 32;
        // stage weights (transposed): LW[k][o=tid]
#pragma unroll
        for (int r = 0; r < 8; r++) {
            const float4 wv = *(const float4*)(wrow + kc0 + r * 4);
            LW[(r * 4 + 0) * 260 + tid] = wv.x;
            LW[(r * 4 + 1) * 260 + tid] = wv.y;
            LW[(r * 4 + 2) * 260 + tid] = wv.z;
            LW[(r * 4 + 3) * 260 + tid] = wv.w;
        }
        // stage LN(x) (transposed): LX[k][tok]
        {
            const float4 g4 = *(const float4*)(gamma + kc0 + kk);
            const float4 b4 = *(const float4*)(beta + kc0 + kk);
            const float4 xv = xreg[c];
            LX[(kk + 0) * 36 + tt] = (xv.x - mu) * rs * g4.x + b4.x;
            LX[(kk + 1) * 36 + tt] = (xv.y - mu) * rs * g4.y + b4.y;
            LX[(kk + 2) * 36 + tt] = (xv.z - mu) * rs * g4.z + b4.z;
            LX[(kk + 3) * 36 + tt] = (xv.w - mu) * rs * g4.w + b4.w;
        }
        __syncthreads();
#pragma unroll 8
        for (int kc = 0; kc < 32; kc++) {
            const float4 w4 = *(const float4*)&LW[kc * 260 + cg * 4];
            const float4 xa = *(const float4*)&LX[kc * 36 + tg * 8];
            const float4 xb = *(const float4*)&LX[kc * 36 + tg * 8 + 4];
            fma4(acc[0], xa.x, w4); fma4(acc[1], xa.y, w4);
            fma4(acc[2], xa.z, w4); fma4(acc[3], xa.w, w4);
            fma4(acc[4], xb.x, w4); fma4(acc[5], xb.y, w4);
            fma4(acc[6], xb.z, w4); fma4(acc[7], xb.w, w4);
        }
        __syncthreads();
    }

    // --- epilogue: relu (K,Q), sum-normalize (K,Q), +bs (R) ---
    const int m  = cg >> 4;               // 0=K 1=Q 2=V 3=R (16-lane slices of each wave)
    const int h0 = (cg & 15) * 4;
    if (m < 2) {
#pragma unroll
        for (int i = 0; i < 8; i++) {
            acc[i].x = fmaxf(acc[i].x, 0.f); acc[i].y = fmaxf(acc[i].y, 0.f);
            acc[i].z = fmaxf(acc[i].z, 0.f); acc[i].w = fmaxf(acc[i].w, 0.f);
        }
    }
    // 16-lane row-sum reduction (xor masks stay inside each matrix's lane slice)
    float rsum[8];
#pragma unroll
    for (int i = 0; i < 8; i++) {
        rsum[i] = acc[i].x + acc[i].y + acc[i].z + acc[i].w;
        rsum[i] += __shfl_xor(rsum[i], 1);
        rsum[i] += __shfl_xor(rsum[i], 2);
        rsum[i] += __shfl_xor(rsum[i], 4);
        rsum[i] += __shfl_xor(rsum[i], 8);
    }
    if (m < 2) {
#pragma unroll
        for (int i = 0; i < 8; i++) {
            const float inv = 1.f / (EPS + rsum[i]);
            acc[i].x *= inv; acc[i].y *= inv; acc[i].z *= inv; acc[i].w *= inv;
        }
    } else if (m == 3) {
        const float4 bv = *(const float4*)(bs + h0);
#pragma unroll
        for (int i = 0; i < 8; i++) {
            acc[i].x += bv.x; acc[i].y += bv.y; acc[i].z += bv.z; acc[i].w += bv.w;
        }
    }
    float* outp = (m == 0) ? Kb : (m == 1) ? Qb : (m == 2) ? Vb : Rb;
#pragma unroll
    for (int ti = 0; ti < 8; ti++)
        *(float4*)(outp + (tok0 + tg * 8 + ti) * Hn + h0) = acc[ti];
    // stash K (normalized) and V in LDS for the chunk kv-sums
    if (m == 0) {
#pragma unroll
        for (int ti = 0; ti < 8; ti++) *(float4*)(Kc + (tg * 8 + ti) * Hn + h0) = acc[ti];
    } else if (m == 2) {
#pragma unroll
        for (int ti = 0; ti < 8; ti++) *(float4*)(Vc + (tg * 8 + ti) * Hn + h0) = acc[ti];
    }
    __syncthreads();

    // --- chunk kv-sums: two 16-token chunks per block ---
    const int jq = tid & 15, rr = tid >> 4;
    const int b  = tok0 >> 10;
    const int c0 = ((tok0 & 1023) >> 5) * 2;   // first of two chunk indices
    float4 a4[4];
    float4* out0 = (float4*)(csum + (size_t)(b * NC + c0) * 4096);
#pragma unroll
    for (int sI = 0; sI < 4; sI++) a4[sI] = f4zero();
    for (int t = 0; t < 16; t++) {
        const float4 kv = ((const float4*)Kc)[t * 16 + jq];
#pragma unroll
        for (int sI = 0; sI < 4; sI++) fma4(a4[sI], Vc[t * Hn + sI * 16 + rr], kv);
    }
#pragma unroll
    for (int sI = 0; sI < 4; sI++) out0[sI * 256 + tid] = a4[sI];
#pragma unroll
    for (int sI = 0; sI < 4; sI++) a4[sI] = f4zero();
    for (int t = 16; t < 32; t++) {
        const float4 kv = ((const float4*)Kc)[t * 16 + jq];
#pragma unroll
        for (int sI = 0; sI < 4; sI++) fma4(a4[sI], Vc[t * Hn + sI * 16 + rr], kv);
    }
#pragma unroll
    for (int sI = 0; sI < 4; sI++) out0[1024 + sI * 256 + tid] = a4[sI];
}

// ---------------- K2: in-place exclusive scan over chunks ----------------
__global__ __launch_bounds__(256) void k2_scan(const float* __restrict__ state,
                                               float* __restrict__ csum) {
    const int b = blockIdx.x >> 4, et = blockIdx.x & 15;
    const int e = et * 256 + threadIdx.x;
    float v[NC];
#pragma unroll
    for (int c = 0; c < NC; c++) v[c] = csum[(size_t)(b * NC + c) * 4096 + e];
    float acc = state[b * 4096 + e];
#pragma unroll
    for (int c = 0; c < NC; c++) {
        csum[(size_t)(b * NC + c) * 4096 + e] = acc;   // exclusive prefix (chunk start)
        acc += v[c];
    }
}

// ---------------- K3: replay chunk, stream S, y + FFN + residual ----------------
__global__ __launch_bounds__(256, 2) void k3_main(
    const float* __restrict__ Kb, const float* __restrict__ Qb, const float* __restrict__ Vb,
    const float* __restrict__ cstart, const float* __restrict__ Rb,
    const float* __restrict__ W1, const float* __restrict__ b1,
    const float* __restrict__ W2, const float* __restrict__ b2,
    float* __restrict__ outY, float* __restrict__ outS) {
    __shared__ float Kc[CSZ * Hn];
    __shared__ float Qc[CSZ * Hn];
    __shared__ float Vc[CSZ * Hn];
    __shared__ float WT[2][64 * 68];   // transposed [k][h]
    __shared__ float Yl[CSZ * 68];     // y per token (pitch 68)
    __shared__ float Y2[CSZ * 68];
    __shared__ float Lb[2][64];
    const int tid = threadIdx.x;
    const int b = blockIdx.x >> 6, c = blockIdx.x & 63;
    const int t0 = c * CSZ;
    // stage K,Q,V (16 tok x 64 = 256 float4 each)
    ((float4*)Kc)[tid] = ((const float4*)(Kb + (b * Tn + t0) * Hn))[tid];
    ((float4*)Qc)[tid] = ((const float4*)(Qb + (b * Tn + t0) * Hn))[tid];
    ((float4*)Vc)[tid] = ((const float4*)(Vb + (b * Tn + t0) * Hn))[tid];
    // stage W1,W2 transposed: 1024 float4 each -> 4 rounds of 256
#pragma unroll
    for (int mat = 0; mat < 2; mat++) {
        const float4* Wg = (const float4*)(mat ? W2 : W1);
#pragma unroll
        for (int r = 0; r < 4; r++) {
            const int f4i = tid + 256 * r;   // 0..1023
            const float4 wv = Wg[f4i];
            const int h = f4i >> 4;          // output row
            const int k = (f4i & 15) * 4;    // input col
            WT[mat][(k + 0) * 68 + h] = wv.x;
            WT[mat][(k + 1) * 68 + h] = wv.y;
            WT[mat][(k + 2) * 68 + h] = wv.z;
            WT[mat][(k + 3) * 68 + h] = wv.w;
        }
    }
    if (tid < 64) Lb[0][tid] = b1[tid];
    else if (tid < 128) Lb[1][tid - 64] = b2[tid - 64];
    // chunk-start state
    float4 S4[4];
    const float4* cs = (const float4*)(cstart + (size_t)(b * NC + c) * 4096);
#pragma unroll
    for (int sI = 0; sI < 4; sI++) S4[sI] = cs[sI * 256 + tid];
    __syncthreads();

    const int jq = tid & 15, rr = tid >> 4;
    float4* SBase = (float4*)outS + (size_t)(b * Tn + t0) * 1024;
    for (int t = 0; t < CSZ; t++) {
        const float4 kv = ((const float4*)Kc)[t * 16 + jq];
        const float4 qv = ((const float4*)Qc)[t * 16 + jq];
        float yp[4];
#pragma unroll
        for (int sI = 0; sI < 4; sI++) {
            fma4(S4[sI], Vc[t * Hn + sI * 16 + rr], kv);
            yp[sI] = S4[sI].x * qv.x + S4[sI].y * qv.y + S4[sI].z * qv.z + S4[sI].w * qv.w;
        }
        float4* So = SBase + t * 1024;
#pragma unroll
        for (int sI = 0; sI < 4; sI++) So[sI * 256 + tid] = S4[sI];
#pragma unroll
        for (int sI = 0; sI < 4; sI++) {
            yp[sI] += __shfl_xor(yp[sI], 1);
            yp[sI] += __shfl_xor(yp[sI], 2);
            yp[sI] += __shfl_xor(yp[sI], 4);
            yp[sI] += __shfl_xor(yp[sI], 8);
        }
        if (jq == 0) {
#pragma unroll
            for (int sI = 0; sI < 4; sI++) Yl[t * 68 + sI * 16 + rr] = yp[sI];
        }
    }
    __syncthreads();

    // --- FFN: thread = (token tg, output quad cg) ---
    const int tg = tid >> 4, cg = tid & 15;
    float4 a = *(const float4*)&Lb[0][cg * 4];
#pragma unroll 16
    for (int k = 0; k < 64; k++)
        fma4(a, Yl[tg * 68 + k], *(const float4*)&WT[0][k * 68 + cg * 4]);
    a.x = fmaxf(a.x, 0.f); a.y = fmaxf(a.y, 0.f); a.z = fmaxf(a.z, 0.f); a.w = fmaxf(a.w, 0.f);
    *(float4*)&Y2[tg * 68 + cg * 4] = a;
    __syncthreads();
    float4 o = *(const float4*)&Lb[1][cg * 4];
#pragma unroll 16
    for (int k = 0; k < 64; k++)
        fma4(o, Y2[tg * 68 + k], *(const float4*)&WT[1][k * 68 + cg * 4]);
    const float4 r4 = ((const float4*)(Rb + (b * Tn + t0) * Hn))[tid];  // same (tg,cg) mapping
    o.x = fmaxf(o.x, 0.f) + r4.x; o.y = fmaxf(o.y, 0.f) + r4.y;
    o.z = fmaxf(o.z, 0.f) + r4.z; o.w = fmaxf(o.w, 0.f) + r4.w;
    ((float4*)(outY + (b * Tn + t0) * Hn))[tid] = o;
}

extern "C" void kernel_launch(void* const* d_in, const int* in_sizes, int n_in,
                              void* d_out, int out_size, void* d_ws, size_t ws_size,
                              hipStream_t stream) {
    const float* x     = (const float*)d_in[0];
    const float* state = (const float*)d_in[1];
    const float* Wk    = (const float*)d_in[2];
    const float* Wq    = (const float*)d_in[3];
    const float* Wv    = (const float*)d_in[4];
    const float* gamma = (const float*)d_in[5];
    const float* beta  = (const float*)d_in[6];
    const float* W1    = (const float*)d_in[7];
    const float* b1    = (const float*)d_in[8];
    const float* W2    = (const float*)d_in[9];
    const float* b2    = (const float*)d_in[10];
    const float* Wsp   = (const float*)d_in[11];
    const float* bs    = (const float*)d_in[12];

    float* ws   = (float*)d_ws;
    float* Kb   = ws;                 // 524288 floats (2 MB)
    float* Qb   = ws + 524288;
    float* Vb   = ws + 1048576;
    float* Rb   = ws + 1572864;
    float* csum = ws + 2097152;       // 8*64*4096 floats (8 MB); scanned in-place -> chunk starts

    float* outY = (float*)d_out;
    float* outS = outY + (size_t)Bn * Tn * Hn;

    k1_proj<<<256, 256, 0, stream>>>(x, gamma, beta, Wk, Wq, Wv, Wsp, bs, Kb, Qb, Vb, Rb, csum);
    k2_scan<<<128, 256, 0, stream>>>(state, csum);
    k3_main<<<512, 256, 0, stream>>>(Kb, Qb, Vb, csum, Rb, W1, b1, W2, b2, outY, outS);
}